// Round 7
// baseline (975.132 us; speedup 1.0000x reference)
//
#include <hip/hip_runtime.h>
#include <math.h>

#define B_  32
#define L_  256
#define PD_ 164
#define D_  240
#define H_  16
#define NB_ 6
#define NC_ 250
#define DK_ 15
#define HID_ 480
#define LP_ 257
#define KP_ 288            // keys padded to 9*32
#define SCALE_ 0.2581988897471611f   // 1/sqrt(15)
#define LOG2E_ 1.4426950408889634f

typedef __attribute__((ext_vector_type(8))) short bf16x8;
typedef __attribute__((ext_vector_type(8))) _Float16 f16x8;
typedef __attribute__((ext_vector_type(4))) float f32x4;

static __device__ inline unsigned short f2bf(float x) {
    unsigned u = __builtin_bit_cast(unsigned, x);
    u += 0x7FFFu + ((u >> 16) & 1u);     // RNE (finite values only)
    return (unsigned short)(u >> 16);
}
static __device__ inline unsigned short f2h(float x) {
    _Float16 h = (_Float16)x;
    return __builtin_bit_cast(unsigned short, h);
}

// async global->LDS, 16B per lane; lds dest must be wave-uniform base (+lane*16)
static __device__ inline void gl2lds16(const void* g, void* l) {
    __builtin_amdgcn_global_load_lds(
        (const __attribute__((address_space(1))) unsigned int*)g,
        (__attribute__((address_space(3))) unsigned int*)l, 16, 0, 0);
}

// ---------------- mask ----------------
__global__ void mask_kernel(const float* __restrict__ x, float* __restrict__ mask) {
    int idx = blockIdx.x * blockDim.x + threadIdx.x;
    if (idx >= B_ * LP_) return;
    int b = idx / LP_, l = idx % LP_;
    if (l == 0) { mask[idx] = 0.f; return; }
    const float* xr = x + ((size_t)b * L_ + (l - 1)) * PD_;
    float mx = -1e30f;
    for (int j = 0; j < PD_; j++) mx = fmaxf(mx, xr[j]);
    mask[idx] = (mx == 0.f) ? 1.f : 0.f;
}

// --------- prep_misc: cvt_x rows (0..8191) + pack_bias (8192..8197) ----------
__global__ void prep_misc(const float* __restrict__ x, unsigned short* __restrict__ xbf,
                          const float* __restrict__ bq, const float* __restrict__ bk,
                          const float* __restrict__ bv, float* __restrict__ b720) {
    int bx = blockIdx.x;
    if (bx < 8192) {
        const float* src = x + (size_t)bx * PD_;
        unsigned short* dst = xbf + (size_t)bx * 192;
        for (int k = threadIdx.x; k < 192; k += 64)
            dst[k] = f2bf(k < PD_ ? src[k] : 0.f);
    } else {
        int i = bx - 8192;           // layer
        for (int n = threadIdx.x; n < 720; n += 64) {
            float v = (n < 240) ? bq[i * 240 + n]
                    : (n < 480) ? bk[i * 240 + n - 240]
                                : bv[i * 240 + n - 480];
            b720[i * 720 + n] = v;
        }
    }
}

// --------- prep_weights: all pretranspose jobs in one dispatch ---------------
// grid (480, 38): y = job, x = output column n
__global__ void prep_weights(const float* __restrict__ e_W1, const float* __restrict__ e_W2,
                             const float* __restrict__ Wq, const float* __restrict__ Wk,
                             const float* __restrict__ Wv, const float* __restrict__ Wo,
                             const float* __restrict__ W1, const float* __restrict__ W2,
                             unsigned short* __restrict__ We1, unsigned short* __restrict__ We2,
                             unsigned short* __restrict__ Wqkv, unsigned short* __restrict__ WoT,
                             unsigned short* __restrict__ W1T, unsigned short* __restrict__ W2T) {
    int job = blockIdx.y, n = blockIdx.x;
    const float* src; unsigned short* dst; int K, N, Kpad;
    if (job == 0)      { src = e_W1; dst = We1; K = PD_; N = 480; Kpad = 192; }
    else if (job == 1) { src = e_W2; dst = We2; K = 480; N = 240; Kpad = 480; }
    else {
        int i = (job - 2) % 6, w = (job - 2) / 6;
        if (w == 0)      { src = Wq + (size_t)i*240*240; dst = Wqkv + (size_t)i*768*256;           K=240; N=240; Kpad=256; }
        else if (w == 1) { src = Wk + (size_t)i*240*240; dst = Wqkv + (size_t)i*768*256 + 240*256; K=240; N=240; Kpad=256; }
        else if (w == 2) { src = Wv + (size_t)i*240*240; dst = Wqkv + (size_t)i*768*256 + 480*256; K=240; N=240; Kpad=256; }
        else if (w == 3) { src = Wo + (size_t)i*240*240; dst = WoT + (size_t)i*256*256;            K=240; N=240; Kpad=256; }
        else if (w == 4) { src = W1 + (size_t)i*240*480; dst = W1T + (size_t)i*512*256;            K=240; N=480; Kpad=256; }
        else             { src = W2 + (size_t)i*480*240; dst = W2T + (size_t)i*256*480;            K=480; N=240; Kpad=480; }
    }
    if (n >= N) return;
    dst += (size_t)n * Kpad;
    for (int k = threadIdx.x; k < Kpad; k += 64)
        dst[k] = f2bf(k < K ? src[(size_t)k * N + n] : 0.f);
}

// ---------------- MFMA GEMM (templated tile width BN = 64 or 128) ------------
// tile 128xBN, 4 waves, K-step 32, staging via global_load_lds (16B/lane).
// flags: 1 relu, 2 accumulate fp32 C, 4 QKV-packed epilogue, 8 bf16 out
template<int BN>
__global__ __launch_bounds__(256)
void gemm_t(const unsigned short* __restrict__ A,
            const unsigned short* __restrict__ Bt,
            const float* __restrict__ bias,
            float* __restrict__ C, unsigned short* __restrict__ Cbf,
            unsigned short* __restrict__ qp, unsigned short* __restrict__ kp,
            unsigned short* __restrict__ vp,
            int M, int N, int Kpad, int Cstride, int flags)
{
    constexpr int NJ = BN / 32;
    __shared__ __align__(16) unsigned short As[128 * 32];
    __shared__ __align__(16) unsigned short Bs[BN * 32];
    const int tid = threadIdx.x;
    const int bm = blockIdx.x * 128;
    const int bn = blockIdx.y * BN;
    const int wave = tid >> 6, lane = tid & 63;
    const int wm = (wave & 1) * 64, wn = (wave >> 1) * (BN / 2);
    const int lq = lane >> 4, lr = lane & 15;

    f32x4 acc[4][NJ];
    #pragma unroll
    for (int i = 0; i < 4; i++)
        #pragma unroll
        for (int j = 0; j < NJ; j++) acc[i][j] = (f32x4){0.f, 0.f, 0.f, 0.f};

    const int srow = lane >> 2;            // 0..15
    const int schk = (lane & 3) << 3;      // 0,8,16,24
    const unsigned short* ga0 = A + (size_t)(bm + wave * 32 + srow) * Kpad + schk;
    const unsigned short* ga1 = ga0 + (size_t)16 * Kpad;
    char* la0 = (char*)As + wave * 2048;
    char* la1 = la0 + 1024;
    const unsigned short* gb0, *gb1 = nullptr;
    char *lb0, *lb1 = nullptr;
    if constexpr (BN == 64) {
        gb0 = Bt + (size_t)(bn + wave * 16 + srow) * Kpad + schk;
        lb0 = (char*)Bs + wave * 1024;
    } else {
        gb0 = Bt + (size_t)(bn + wave * 32 + srow) * Kpad + schk;
        gb1 = gb0 + (size_t)16 * Kpad;
        lb0 = (char*)Bs + wave * 2048;
        lb1 = lb0 + 1024;
    }

    const int nkt = Kpad >> 5;
    for (int kt = 0; kt < nkt; kt++) {
        gl2lds16(ga0, la0);
        gl2lds16(ga1, la1);
        gl2lds16(gb0, lb0);
        if constexpr (BN == 128) gl2lds16(gb1, lb1);
        ga0 += 32; ga1 += 32; gb0 += 32;
        if constexpr (BN == 128) gb1 += 32;
        __syncthreads();
        bf16x8 af[4], bfr[NJ];
        #pragma unroll
        for (int i = 0; i < 4; i++)
            af[i] = *(const bf16x8*)&As[(wm + i * 16 + lr) * 32 + lq * 8];
        #pragma unroll
        for (int j = 0; j < NJ; j++)
            bfr[j] = *(const bf16x8*)&Bs[(wn + j * 16 + lr) * 32 + lq * 8];
        #pragma unroll
        for (int i = 0; i < 4; i++)
            #pragma unroll
            for (int j = 0; j < NJ; j++)
                acc[i][j] = __builtin_amdgcn_mfma_f32_16x16x32_bf16(af[i], bfr[j], acc[i][j], 0, 0, 0);
        __syncthreads();
    }

    if (flags & 4) {                       // QKV packed epilogue (N=720)
        #pragma unroll
        for (int j = 0; j < NJ; j++) {
            int n = bn + wn + j * 16 + lr;
            if (n >= N) continue;
            int which = n / 240;
            int rem = n - which * 240;
            int hh = rem / 15;
            int c = rem - hh * 15;
            unsigned short* dst = (which == 0) ? qp : (which == 1) ? kp : vp;
            float bias_n = bias[n];
            float mult = (which == 0) ? (SCALE_ * LOG2E_) : 1.f;
            #pragma unroll
            for (int i = 0; i < 4; i++)
                #pragma unroll
                for (int r = 0; r < 4; r++) {
                    int m = bm + wm + i * 16 + lq * 4 + r;
                    if (m >= M) continue;
                    float s = (acc[i][j][r] + bias_n) * mult;
                    int b = m / LP_, l = m - b * LP_;
                    unsigned short bits = (which == 2) ? f2h(s) : f2bf(s);
                    dst[(((size_t)b * H_ + hh) * LP_ + l) * 16 + c] = bits;
                }
        }
    } else if (flags & 8) {                // bf16 output
        #pragma unroll
        for (int i = 0; i < 4; i++)
            #pragma unroll
            for (int j = 0; j < NJ; j++) {
                int n = bn + wn + j * 16 + lr;
                if (n >= N) continue;
                float bias_n = bias ? bias[n] : 0.f;
                #pragma unroll
                for (int r = 0; r < 4; r++) {
                    int m = bm + wm + i * 16 + lq * 4 + r;
                    if (m >= M) continue;
                    float s = acc[i][j][r] + bias_n;
                    if (flags & 1) s = fmaxf(s, 0.f);
                    Cbf[(size_t)m * Cstride + n] = f2bf(s);
                }
            }
    } else {                               // fp32 output (optionally accumulate)
        #pragma unroll
        for (int i = 0; i < 4; i++)
            #pragma unroll
            for (int j = 0; j < NJ; j++) {
                int n = bn + wn + j * 16 + lr;
                if (n >= N) continue;
                float bias_n = bias ? bias[n] : 0.f;
                #pragma unroll
                for (int r = 0; r < 4; r++) {
                    int m = bm + wm + i * 16 + lq * 4 + r;
                    if (m >= M) continue;
                    float s = acc[i][j][r] + bias_n;
                    if (flags & 1) s = fmaxf(s, 0.f);
                    size_t off = (size_t)m * Cstride + n;
                    if (flags & 2) C[off] += s; else C[off] = s;
                }
            }
    }
}

// ------------- LN240: wave-per-row, fp32 in -> bf16 out [rows][256] ----------
__global__ __launch_bounds__(256)
void ln240(const float* __restrict__ in, unsigned short* __restrict__ out,
           const float* __restrict__ g, const float* __restrict__ bb) {
    const int row = blockIdx.x * 4 + (threadIdx.x >> 6);
    const int lane = threadIdx.x & 63;
    const float* x = in + (size_t)row * 240;
    float4 v = {0.f, 0.f, 0.f, 0.f};
    if (lane < 60) v = *(const float4*)(x + lane * 4);
    float s = (v.x + v.y) + (v.z + v.w);
    #pragma unroll
    for (int off = 32; off; off >>= 1) s += __shfl_xor(s, off);
    const float mean = s * (1.f / 240.f);
    float4 d;
    d.x = v.x - mean; d.y = v.y - mean; d.z = v.z - mean; d.w = v.w - mean;
    float vs = (lane < 60) ? (d.x * d.x + d.y * d.y) + (d.z * d.z + d.w * d.w) : 0.f;
    #pragma unroll
    for (int off = 32; off; off >>= 1) vs += __shfl_xor(vs, off);
    const float rs = rsqrtf(vs * (1.f / 240.f) + 1e-5f);
    ushort4 o4 = {0, 0, 0, 0};
    if (lane < 60) {
        float4 g4 = *(const float4*)(g + lane * 4);
        float4 b4 = *(const float4*)(bb + lane * 4);
        o4.x = f2bf(d.x * rs * g4.x + b4.x);
        o4.y = f2bf(d.y * rs * g4.y + b4.y);
        o4.z = f2bf(d.z * rs * g4.z + b4.z);
        o4.w = f2bf(d.w * rs * g4.w + b4.w);
    }
    *(ushort4*)(out + (size_t)row * 256 + lane * 4) = o4;   // lanes 60..63: pad zeros
}

// ------------- LN480+relu: wave-per-row, fp32 in -> bf16 out [rows][480] -----
__global__ __launch_bounds__(256)
void ln480(const float* __restrict__ in, unsigned short* __restrict__ out,
           const float* __restrict__ g, const float* __restrict__ bb) {
    const int row = blockIdx.x * 4 + (threadIdx.x >> 6);
    const int lane = threadIdx.x & 63;
    const float* x = in + (size_t)row * 480;
    float4 va = {0.f,0.f,0.f,0.f}, vb = {0.f,0.f,0.f,0.f};
    if (lane < 60) {
        va = *(const float4*)(x + lane * 8);
        vb = *(const float4*)(x + lane * 8 + 4);
    }
    float s = ((va.x + va.y) + (va.z + va.w)) + ((vb.x + vb.y) + (vb.z + vb.w));
    #pragma unroll
    for (int off = 32; off; off >>= 1) s += __shfl_xor(s, off);
    const float mean = s * (1.f / 480.f);
    float4 da, db;
    da.x = va.x - mean; da.y = va.y - mean; da.z = va.z - mean; da.w = va.w - mean;
    db.x = vb.x - mean; db.y = vb.y - mean; db.z = vb.z - mean; db.w = vb.w - mean;
    float vs = (lane < 60) ? ((da.x*da.x + da.y*da.y) + (da.z*da.z + da.w*da.w)) +
                             ((db.x*db.x + db.y*db.y) + (db.z*db.z + db.w*db.w)) : 0.f;
    #pragma unroll
    for (int off = 32; off; off >>= 1) vs += __shfl_xor(vs, off);
    const float rs = rsqrtf(vs * (1.f / 480.f) + 1e-5f);
    if (lane < 60) {
        float4 ga = *(const float4*)(g + lane * 8);
        float4 gb = *(const float4*)(g + lane * 8 + 4);
        float4 ba = *(const float4*)(bb + lane * 8);
        float4 b2 = *(const float4*)(bb + lane * 8 + 4);
        ushort4 oa, ob;
        oa.x = f2bf(fmaxf(da.x * rs * ga.x + ba.x, 0.f));
        oa.y = f2bf(fmaxf(da.y * rs * ga.y + ba.y, 0.f));
        oa.z = f2bf(fmaxf(da.z * rs * ga.z + ba.z, 0.f));
        oa.w = f2bf(fmaxf(da.w * rs * ga.w + ba.w, 0.f));
        ob.x = f2bf(fmaxf(db.x * rs * gb.x + b2.x, 0.f));
        ob.y = f2bf(fmaxf(db.y * rs * gb.y + b2.y, 0.f));
        ob.z = f2bf(fmaxf(db.z * rs * gb.z + b2.z, 0.f));
        ob.w = f2bf(fmaxf(db.w * rs * gb.w + b2.w, 0.f));
        *(ushort4*)(out + (size_t)row * 480 + lane * 8) = oa;
        *(ushort4*)(out + (size_t)row * 480 + lane * 8 + 4) = ob;
    }
}

// -------- embed finish: wave-per-row LN(g2)+relu+pos (cls for l==0) ----------
// also initializes q/k/v col-15 constants (lanes 60..62), replacing attn_init.
__global__ __launch_bounds__(256)
void embed_finish(const float* __restrict__ tmp, const float* __restrict__ mask,
                  const float* __restrict__ g, const float* __restrict__ bb,
                  const float* __restrict__ pos, const float* __restrict__ cls,
                  float* __restrict__ h,
                  unsigned short* __restrict__ qp, unsigned short* __restrict__ kp,
                  unsigned short* __restrict__ vp) {
    const int row = blockIdx.x * 4 + (threadIdx.x >> 6);
    const int lane = threadIdx.x & 63;
    const int b = row / LP_, l = row - b * LP_;
    float* outr = h + (size_t)row * 240;

    // q/k/v col-15 init for this (b,l) across all 16 heads
    if (lane >= 60 && lane <= 62) {
        unsigned short bits;
        unsigned short* dst;
        if (lane == 60) { bits = f2bf(LOG2E_); dst = qp; }
        else if (lane == 61) { bits = (mask[row] != 0.f) ? f2bf(-10000.f) : 0; dst = kp; }
        else { bits = f2h(1.f); dst = vp; }
        #pragma unroll
        for (int hh = 0; hh < H_; hh++)
            dst[(((size_t)b * H_ + hh) * LP_ + l) * 16 + 15] = bits;
    }

    if (l == 0) {
        if (lane < 60) *(float4*)(outr + lane * 4) = *(const float4*)(cls + lane * 4);
        return;
    }
    const float* x = tmp + ((size_t)b * L_ + (l - 1)) * 240;
    float4 v = {0.f, 0.f, 0.f, 0.f};
    if (lane < 60) v = *(const float4*)(x + lane * 4);
    float s = (v.x + v.y) + (v.z + v.w);
    #pragma unroll
    for (int off = 32; off; off >>= 1) s += __shfl_xor(s, off);
    const float mean = s * (1.f / 240.f);
    float4 d;
    d.x = v.x - mean; d.y = v.y - mean; d.z = v.z - mean; d.w = v.w - mean;
    float vs = (lane < 60) ? (d.x * d.x + d.y * d.y) + (d.z * d.z + d.w * d.w) : 0.f;
    #pragma unroll
    for (int off = 32; off; off >>= 1) vs += __shfl_xor(vs, off);
    const float rs = rsqrtf(vs * (1.f / 240.f) + 1e-5f);
    if (lane < 60) {
        float4 g4 = *(const float4*)(g + lane * 4);
        float4 b4 = *(const float4*)(bb + lane * 4);
        float4 p4 = *(const float4*)(pos + (size_t)(l - 1) * 240 + lane * 4);
        float4 o;
        o.x = fmaxf(d.x * rs * g4.x + b4.x, 0.f) + p4.x;
        o.y = fmaxf(d.y * rs * g4.y + b4.y, 0.f) + p4.y;
        o.z = fmaxf(d.z * rs * g4.z + b4.z, 0.f) + p4.z;
        o.w = fmaxf(d.w * rs * g4.w + b4.w, 0.f) + p4.w;
        *(float4*)(outr + lane * 4) = o;
    }
}

// ---------------- MFMA flash attention: block per (b,h), 4 waves -------------
__global__ __launch_bounds__(256)
void attn_mfma(const unsigned short* __restrict__ qp, const unsigned short* __restrict__ kp,
               const unsigned short* __restrict__ vp, unsigned short* __restrict__ obf)
{
    __shared__ __align__(16) unsigned short Kl[KP_ * 24];    // 13.5 KB
    __shared__ __align__(16) unsigned short Vt[16 * 296];    // 9.25 KB  V^T f16
    __shared__ __align__(16) unsigned short Pl[4][16 * 296]; // 37 KB    P f16 per wave
    const int hh = blockIdx.x, b = blockIdx.y;
    const int tid = threadIdx.x;
    const int wave = tid >> 6, lane = tid & 63;
    const int lq = lane >> 4, lr = lane & 15;
    const size_t base = ((size_t)b * H_ + hh) * LP_ * 16;

    for (int key = tid; key < KP_; key += 256) {
        uint4 z = {0u, 0u, 0u, 0u};
        uint4 k0 = z, k1 = z, v0 = z, v1 = z;
        if (key < LP_) {
            k0 = *(const uint4*)(kp + base + (size_t)key * 16);
            k1 = *(const uint4*)(kp + base + (size_t)key * 16 + 8);
            v0 = *(const uint4*)(vp + base + (size_t)key * 16);
            v1 = *(const uint4*)(vp + base + (size_t)key * 16 + 8);
        } else {
            k1.w = 0xC61C0000u;            // elem15 = bf16(-10000) sentinel
        }
        *(uint4*)&Kl[key * 24] = k0;
        *(uint4*)&Kl[key * 24 + 8] = k1;
        unsigned short vs[8];
        *(uint4*)vs = v0;
        #pragma unroll
        for (int d = 0; d < 8; d++) Vt[d * 296 + key] = vs[d];
        *(uint4*)vs = v1;
        #pragma unroll
        for (int d = 0; d < 8; d++) Vt[(d + 8) * 296 + key] = vs[d];
    }
    __syncthreads();

    unsigned short* Pw = &Pl[wave][0];
    for (int qt = wave; qt < 17; qt += 4) {
        const int qrow = qt * 16 + lr;
        bf16x8 aq = {0, 0, 0, 0, 0, 0, 0, 0};
        if (lq < 2)
            aq = *(const bf16x8*)(qp + base + (size_t)qrow * 16 + lq * 8);
        for (int kt = 0; kt < 18; kt++) {
            bf16x8 bk = {0, 0, 0, 0, 0, 0, 0, 0};
            if (lq < 2)
                bk = *(const bf16x8*)&Kl[(kt * 16 + lr) * 24 + lq * 8];
            f32x4 sacc = {0.f, 0.f, 0.f, 0.f};
            sacc = __builtin_amdgcn_mfma_f32_16x16x32_bf16(aq, bk, sacc, 0, 0, 0);
            #pragma unroll
            for (int r = 0; r < 4; r++)
                Pw[(lq * 4 + r) * 296 + kt * 16 + lr] = f2h(exp2f(sacc[r]));
        }
        asm volatile("s_waitcnt lgkmcnt(0)" ::: "memory");
        f32x4 o = {0.f, 0.f, 0.f, 0.f};
        #pragma unroll
        for (int ks = 0; ks < 9; ks++) {
            f16x8 ap = *(const f16x8*)&Pw[lr * 296 + ks * 32 + lq * 8];
            f16x8 bv = *(const f16x8*)&Vt[lr * 296 + ks * 32 + lq * 8];
            o = __builtin_amdgcn_mfma_f32_16x16x32_f16(ap, bv, o, 0, 0, 0);
        }
        asm volatile("s_waitcnt lgkmcnt(0)" ::: "memory");
        #pragma unroll
        for (int r = 0; r < 4; r++) {
            float denom = __shfl(o[r], lane | 15);
            int q = qt * 16 + lq * 4 + r;
            if (q < LP_ && lr < 15)
                obf[((size_t)b * LP_ + q) * 256 + hh * DK_ + lr] = f2bf(o[r] / denom);
        }
    }
    // zero pad cols 240..255 (once per row, by hh==0 block)
    if (hh == 0) {
        for (int q = tid; q < LP_; q += 256) {
            uint4 z = {0u, 0u, 0u, 0u};
            *(uint4*)(obf + ((size_t)b * LP_ + q) * 256 + 240) = z;
            *(uint4*)(obf + ((size_t)b * LP_ + q) * 256 + 248) = z;
        }
    }
}

// ---------------- masked mean pool (partial) ---------------------------------
__global__ void pool_partial(const float* __restrict__ h, const float* __restrict__ mask,
                             float* __restrict__ partial) {
    int b = blockIdx.x, slice = blockIdx.y;
    int d = threadIdx.x;
    if (d >= D_) return;
    float s = 0.f;
    int l0 = slice * 29;
    for (int i = 0; i < 29; i++) {
        int l = l0 + i;
        if (l < LP_ && mask[b * LP_ + l] == 0.f)
            s += h[((size_t)b * LP_ + l) * D_ + d];
    }
    partial[((size_t)b * 9 + slice) * D_ + d] = s;
}

// ---------------- pool finalize + logits -------------------------------------
__global__ __launch_bounds__(256)
void pool_logits(const float* __restrict__ partial, const float* __restrict__ mask,
                 const float* __restrict__ W, const float* __restrict__ bias,
                 float* __restrict__ out) {
    int b = blockIdx.x;
    int t = threadIdx.x;
    __shared__ float red[256];
    __shared__ float pool[240];
    float c = 0.f;
    for (int l = t; l < LP_; l += 256) c += (mask[b * LP_ + l] == 0.f) ? 1.f : 0.f;
    red[t] = c;
    __syncthreads();
    for (int off = 128; off > 0; off >>= 1) {
        if (t < off) red[t] += red[t + off];
        __syncthreads();
    }
    float inv = 1.f / red[0];
    if (t < D_) {
        float s = 0.f;
        #pragma unroll
        for (int sl = 0; sl < 9; sl++) s += partial[((size_t)b * 9 + sl) * D_ + t];
        pool[t] = s * inv;
    }
    __syncthreads();
    if (t < NC_) {
        float s = bias[t];
        for (int kk = 0; kk < D_; kk++) s += pool[kk] * W[(size_t)kk * NC_ + t];
        out[b * NC_ + t] = s;
    }
}

extern "C" void kernel_launch(void* const* d_in, const int* in_sizes, int n_in,
                              void* d_out, int out_size, void* d_ws, size_t ws_size,
                              hipStream_t stream) {
    const float* x        = (const float*)d_in[0];
    const float* pos      = (const float*)d_in[1];
    const float* cls      = (const float*)d_in[2];
    const float* e_W1     = (const float*)d_in[3];
    const float* e_b1     = (const float*)d_in[4];
    const float* e_g1     = (const float*)d_in[5];
    const float* e_bn1    = (const float*)d_in[6];
    const float* e_W2     = (const float*)d_in[7];
    const float* e_b2     = (const float*)d_in[8];
    const float* e_g2     = (const float*)d_in[9];
    const float* e_bn2    = (const float*)d_in[10];
    const float* ln1_g    = (const float*)d_in[11];
    const float* ln1_b    = (const float*)d_in[12];
    const float* Wq       = (const float*)d_in[13];
    const float* bq       = (const float*)d_in[14];
    const float* Wk       = (const float*)d_in[15];
    const float* bk       = (const float*)d_in[16];
    const float* Wv       = (const float*)d_in[17];
    const float* bv       = (const float*)d_in[18];
    const float* Wo       = (const float*)d_in[19];
    const float* bo       = (const float*)d_in[20];
    const float* ln2_g    = (const float*)d_in[21];
    const float* ln2_b    = (const float*)d_in[22];
    const float* W1       = (const float*)d_in[23];
    const float* b1       = (const float*)d_in[24];
    const float* W2       = (const float*)d_in[25];
    const float* b2       = (const float*)d_in[26];
    const float* logit_W  = (const float*)d_in[27];
    const float* logit_b  = (const float*)d_in[28];
    float* out = (float*)d_out;

    const size_t TOK  = (size_t)B_ * LP_;            // 8224
    const size_t TOKP = 8320;                        // padded to 65*128
    const size_t HN   = TOK * D_;
    const size_t QN   = (size_t)B_ * H_ * LP_ * 16;  // 2,105,344

    char* wsb = (char*)d_ws;
    size_t cur = 0;
    auto take = [&](size_t bytes) { void* p = wsb + cur; cur += (bytes + 15) & ~15ULL; return p; };
    float* mask = (float*)take(8224 * 4);
    float* h    = (float*)take(HN * 4);
    float* b720 = (float*)take(NB_ * 720 * 4);
    float* part = (float*)take((size_t)B_ * 9 * D_ * 4);
    void* regionA = take((size_t)8192 * 480 * 4);
    float* tmp1 = (float*)regionA;
    unsigned short* tbf = (unsigned short*)regionA;
    void* regionB = take(TOKP * 256 * 2 * 2);
    float* y32 = (float*)regionB;
    unsigned short* ybf = (unsigned short*)regionB;
    unsigned short* obf = ybf + TOKP * 256;
    unsigned short* xbf  = (unsigned short*)take((size_t)8192 * 192 * 2);
    unsigned short* We1  = (unsigned short*)take((size_t)512 * 192 * 2);
    unsigned short* We2  = (unsigned short*)take((size_t)256 * 480 * 2);
    unsigned short* Wqkv = (unsigned short*)take((size_t)NB_ * 768 * 256 * 2);
    unsigned short* WoT  = (unsigned short*)take((size_t)NB_ * 256 * 256 * 2);
    unsigned short* W1T  = (unsigned short*)take((size_t)NB_ * 512 * 256 * 2);
    unsigned short* W2T  = (unsigned short*)take((size_t)NB_ * 256 * 480 * 2);
    unsigned short* qp = (unsigned short*)take(QN * 3 * 2 + 16 * 16 * 2);
    unsigned short* kp = qp + QN;
    unsigned short* vp = kp + QN;
    unsigned short* t480bf = qp;   // aliases qp/kp, dead before embed_finish

    const int BS = 256;
    auto blocks = [](size_t n) { return (int)((n + 255) / 256); };

    // prep (3 dispatches)
    mask_kernel<<<blocks(TOK), BS, 0, stream>>>(x, mask);
    prep_misc<<<8192 + NB_, 64, 0, stream>>>(x, xbf, bq, bk, bv, b720);
    prep_weights<<<dim3(480, 38), 64, 0, stream>>>(e_W1, e_W2, Wq, Wk, Wv, Wo, W1, W2,
                                                   We1, We2, Wqkv, WoT, W1T, W2T);

    // embed
    gemm_t<128><<<dim3(64, 4), BS, 0, stream>>>(xbf, We1, e_b1, tmp1, nullptr,
                                                nullptr, nullptr, nullptr,
                                                8192, 480, 192, 480, 0);
    ln480<<<2048, BS, 0, stream>>>(tmp1, t480bf, e_g1, e_bn1);
    gemm_t<64><<<dim3(64, 4), BS, 0, stream>>>(t480bf, We2, e_b2, y32, nullptr,
                                               nullptr, nullptr, nullptr,
                                               8192, 240, 480, 240, 0);
    embed_finish<<<(int)(TOK / 4), BS, 0, stream>>>(y32, mask, e_g2, e_bn2, pos, cls, h,
                                                    qp, kp, vp);

    for (int i = 0; i < NB_; i++) {
        ln240<<<(int)(TOK / 4), BS, 0, stream>>>(h, ybf, ln1_g + i * D_, ln1_b + i * D_);
        gemm_t<128><<<dim3(65, 6), BS, 0, stream>>>(ybf, Wqkv + (size_t)i * 768 * 256,
                                                    b720 + i * 720, nullptr, nullptr,
                                                    qp, kp, vp,
                                                    (int)TOK, 720, 256, 0, 4);
        attn_mfma<<<dim3(H_, B_), BS, 0, stream>>>(qp, kp, vp, obf);
        gemm_t<64><<<dim3(65, 4), BS, 0, stream>>>(obf, WoT + (size_t)i * 256 * 256,
                                                   bo + i * D_, h, nullptr,
                                                   nullptr, nullptr, nullptr,
                                                   (int)TOK, 240, 256, 240, 2);
        ln240<<<(int)(TOK / 4), BS, 0, stream>>>(h, ybf, ln2_g + i * D_, ln2_b + i * D_);
        gemm_t<128><<<dim3(65, 4), BS, 0, stream>>>(ybf, W1T + (size_t)i * 512 * 256,
                                                    b1 + i * HID_, nullptr, tbf,
                                                    nullptr, nullptr, nullptr,
                                                    (int)TOK, 480, 256, 480, 1 | 8);
        gemm_t<64><<<dim3(65, 4), BS, 0, stream>>>(tbf, W2T + (size_t)i * 256 * 480,
                                                   b2 + i * D_, h, nullptr,
                                                   nullptr, nullptr, nullptr,
                                                   (int)TOK, 240, 480, 240, 2);
    }

    pool_partial<<<dim3(B_, 9), BS, 0, stream>>>(h, mask, part);
    pool_logits<<<B_, BS, 0, stream>>>(part, mask, logit_W, logit_b, out);
}